// Round 1
// baseline (429.859 us; speedup 1.0000x reference)
//
#include <hip/hip_runtime.h>
#include <math.h>

// ---------------------------------------------------------------------------
// LearnableDCTNet.
//   low  = C^T ((C X C^T) * Q) C ;  high = X - low
// C compile-time constant (exact DCT-II; differs from reference's
// truncated-pi basis by <2e-7/entry -> ~1e-5 at output; threshold 1.08e-1).
// Round 4: byte-identical resubmission of the round-3 verified kernel
// (430.1 us) — the round-3 bench died to an infra failure, so this round
// re-establishes the baseline AND captures the rocprof counters needed to
// decide between the latency/occupancy theory (VGPR~160+, 3 waves/SIMD) and
// the scratch-spill theory (FETCH+WRITE >> 402 MB ideal).
// ---------------------------------------------------------------------------

typedef float f4 __attribute__((ext_vector_type(4)));

// cos(k*pi/16), k = 0..31 (full period)
__host__ __device__ constexpr float cc(int i, int j) {
  constexpr double COS16[32] = {
     1.0,
     0.98078528040323043,
     0.92387953251128674,
     0.83146961230254524,
     0.70710678118654752,
     0.55557023301960222,
     0.38268343236508977,
     0.19509032201612827,
     0.0,
    -0.19509032201612827,
    -0.38268343236508977,
    -0.55557023301960222,
    -0.70710678118654752,
    -0.83146961230254524,
    -0.92387953251128674,
    -0.98078528040323043,
    -1.0,
    -0.98078528040323043,
    -0.92387953251128674,
    -0.83146961230254524,
    -0.70710678118654752,
    -0.55557023301960222,
    -0.38268343236508977,
    -0.19509032201612827,
     0.0,
     0.19509032201612827,
     0.38268343236508977,
     0.55557023301960222,
     0.70710678118654752,
     0.83146961230254524,
     0.92387953251128674,
     0.98078528040323043,
  };
  // C[0][j] = sqrt(1/8); C[i][j] = 0.5 * cos(pi*i*(2j+1)/16)
  return (i == 0) ? 0.35355339059327373f
                  : (float)(0.5 * COS16[(i * (2 * j + 1)) % 32]);
}

// ---------------------------------------------------------------------------
// Setup: noise MLP (exact-erf GELU) in fp64 -> Q (64 floats) in d_ws.
// ---------------------------------------------------------------------------
__global__ void setup_q(const float* __restrict__ noise,
                        const float* __restrict__ qmat,
                        const float* __restrict__ qmw,
                        const float* __restrict__ w1, const float* __restrict__ b1,
                        const float* __restrict__ w2, const float* __restrict__ b2,
                        const float* __restrict__ w3, const float* __restrict__ b3,
                        float* __restrict__ qout) {
  __shared__ double coeff[16];
  if (threadIdx.x == 0) {
    const double inv_sqrt2 = 0.70710678118654752;
    double h1[16], h2[16], nr[18];
    double nl = (double)noise[0];
    for (int j = 0; j < 16; ++j) {
      double v = nl * (double)w1[j] + (double)b1[j];
      h1[j] = 0.5 * v * (1.0 + erf(v * inv_sqrt2));
    }
    for (int j = 0; j < 16; ++j) {
      double v = (double)b2[j];
      for (int i = 0; i < 16; ++i) v += h1[i] * (double)w2[i * 16 + j];
      h2[j] = 0.5 * v * (1.0 + erf(v * inv_sqrt2));
    }
    for (int j = 0; j < 18; ++j) {
      double v = (double)b3[j];
      for (int i = 0; i < 16; ++i) v += h2[i] * (double)w3[i * 18 + j];
      nr[j] = v;
    }
    double mx = (double)qmw[0];
    for (int i = 1; i < 16; ++i) mx = fmax(mx, (double)qmw[i]);
    double e[16], s = 0.0;
    for (int i = 0; i < 16; ++i) { e[i] = exp((double)qmw[i] - mx); s += e[i]; }
    for (int i = 0; i < 16; ++i)
      coeff[i] = (e[i] / s * nr[0] + nr[1]) * nr[2 + i];
  }
  __syncthreads();
  const int t = threadIdx.x;  // 64 threads, one Q entry each
  double q = 0.0;
  for (int i = 0; i < 16; ++i) q += coeff[i] * (double)qmat[i * 64 + t];
  qout[t] = (float)q;
}

// ---------------------------------------------------------------------------
// Main: one thread per 8x8 block. X kept in 64 regs for high = X - low.
// One barrier (Q -> LDS). NT loads, regular stores.
// ---------------------------------------------------------------------------
__global__ __launch_bounds__(256) void dct_main(const float* __restrict__ x,
                                                const float* __restrict__ qg,
                                                float* __restrict__ lo,
                                                float* __restrict__ hi) {
  __shared__ float Qs[64];
  const int tid = threadIdx.x;
  if (tid < 64) Qs[tid] = qg[tid];
  __syncthreads();

  const int gid = blockIdx.x * 256 + tid;
  // image n = gid>>6, band = (gid>>3)&7, block-col = gid&7 ; W = 64 floats/row
  const int base = ((gid >> 6) << 12) | (((gid >> 3) & 7) << 9) | ((gid & 7) << 3);
  const float* px = x + base;

  float X[8][8];
#pragma unroll
  for (int r = 0; r < 8; ++r) {
    const f4 a = __builtin_nontemporal_load(reinterpret_cast<const f4*>(px + r * 64));
    const f4 b = __builtin_nontemporal_load(reinterpret_cast<const f4*>(px + r * 64 + 4));
    X[r][0] = a.x; X[r][1] = a.y; X[r][2] = a.z; X[r][3] = a.w;
    X[r][4] = b.x; X[r][5] = b.y; X[r][6] = b.z; X[r][7] = b.w;
  }

  float U[8][8];
  // Stage 1: U = X * C^T   (U[r][j] = sum_l X[r][l] * C[j][l])
#pragma unroll
  for (int r = 0; r < 8; ++r) {
#pragma unroll
    for (int j = 0; j < 8; ++j) {
      float s = X[r][0] * cc(j, 0);
#pragma unroll
      for (int l = 1; l < 8; ++l) s = fmaf(X[r][l], cc(j, l), s);
      U[r][j] = s;
    }
  }
  // Stage 2: D = C * U, fused mask: U[i][j] = D[i][j] * Q[i][j]
#pragma unroll
  for (int j = 0; j < 8; ++j) {
    float t[8];
#pragma unroll
    for (int i = 0; i < 8; ++i) {
      float s = cc(i, 0) * U[0][j];
#pragma unroll
      for (int k = 1; k < 8; ++k) s = fmaf(cc(i, k), U[k][j], s);
      t[i] = s;
    }
#pragma unroll
    for (int i = 0; i < 8; ++i) U[i][j] = t[i] * Qs[i * 8 + j];
  }
  // Stage 3: V = M * C   (V[r][j] = sum_k M[r][k] * C[k][j])
#pragma unroll
  for (int r = 0; r < 8; ++r) {
    float t[8];
#pragma unroll
    for (int j = 0; j < 8; ++j) {
      float s = U[r][0] * cc(0, j);
#pragma unroll
      for (int k = 1; k < 8; ++k) s = fmaf(U[r][k], cc(k, j), s);
      t[j] = s;
    }
#pragma unroll
    for (int j = 0; j < 8; ++j) U[r][j] = t[j];
  }
  // Stage 4: low = C^T * V   (low[i][j] = sum_k C[k][i] * V[k][j])
#pragma unroll
  for (int j = 0; j < 8; ++j) {
    float t[8];
#pragma unroll
    for (int i = 0; i < 8; ++i) {
      float s = cc(0, i) * U[0][j];
#pragma unroll
      for (int k = 1; k < 8; ++k) s = fmaf(cc(k, i), U[k][j], s);
      t[i] = s;
    }
#pragma unroll
    for (int i = 0; i < 8; ++i) U[i][j] = t[i];
  }

  float* plo = lo + base;
  float* phi = hi + base;
#pragma unroll
  for (int r = 0; r < 8; ++r) {
    f4 a = {U[r][0], U[r][1], U[r][2], U[r][3]};
    f4 b = {U[r][4], U[r][5], U[r][6], U[r][7]};
    *reinterpret_cast<f4*>(plo + r * 64)     = a;
    *reinterpret_cast<f4*>(plo + r * 64 + 4) = b;
    f4 c = {X[r][0] - U[r][0], X[r][1] - U[r][1],
            X[r][2] - U[r][2], X[r][3] - U[r][3]};
    f4 d = {X[r][4] - U[r][4], X[r][5] - U[r][5],
            X[r][6] - U[r][6], X[r][7] - U[r][7]};
    *reinterpret_cast<f4*>(phi + r * 64)     = c;
    *reinterpret_cast<f4*>(phi + r * 64 + 4) = d;
  }
}

extern "C" void kernel_launch(void* const* d_in, const int* in_sizes, int n_in,
                              void* d_out, int out_size, void* d_ws, size_t ws_size,
                              hipStream_t stream) {
  const float* x   = (const float*)d_in[0];
  const float* nl  = (const float*)d_in[1];
  const float* qm  = (const float*)d_in[2];
  const float* qmw = (const float*)d_in[3];
  const float* w1  = (const float*)d_in[4];
  const float* b1  = (const float*)d_in[5];
  const float* w2  = (const float*)d_in[6];
  const float* b2  = (const float*)d_in[7];
  const float* w3  = (const float*)d_in[8];
  const float* b3  = (const float*)d_in[9];

  const int n_elem = in_sizes[0];          // 33554432
  float* lo = (float*)d_out;
  float* hi = lo + n_elem;
  float* q  = (float*)d_ws;                // 64 floats

  setup_q<<<1, 64, 0, stream>>>(nl, qm, qmw, w1, b1, w2, b2, w3, b3, q);

  const int n_blocks8 = n_elem >> 6;       // 524288 8x8 blocks
  const int grid = n_blocks8 >> 8;         // 2048 workgroups of 256
  dct_main<<<grid, 256, 0, stream>>>(x, q, lo, hi);
}

// Round 2
// 419.329 us; speedup vs baseline: 1.0251x; 1.0251x over previous
//
#include <hip/hip_runtime.h>
#include <math.h>

// ---------------------------------------------------------------------------
// LearnableDCTNet.
//   low  = C^T ((C X C^T) * Q) C ;  high = X - low
// Round 5: wave-cooperative redesign. 8 lanes per 8x8 block (one lane per
// row); one wave64 = one 8-row band = 8 adjacent blocks = 2 KB contiguous.
// All 4 transforms are per-lane row transforms (64 FMA each); the two
// transposes are 3-stage __shfl_xor butterflies (masks 8/16/32; block index
// in lane bits 0-2 is untouched). Per-lane state ~48 VGPR -> 8 waves/SIMD
// (vs ~3 before), dependent chain ~400 ops (vs ~2100).
// NT loads (use-once), regular stores (NT stores = 1.44x write amp, round 3).
// ---------------------------------------------------------------------------

typedef float f4 __attribute__((ext_vector_type(4)));

// cos(k*pi/16), k = 0..31 (full period)
__host__ __device__ constexpr float cc(int i, int j) {
  constexpr double COS16[32] = {
     1.0,
     0.98078528040323043,
     0.92387953251128674,
     0.83146961230254524,
     0.70710678118654752,
     0.55557023301960222,
     0.38268343236508977,
     0.19509032201612827,
     0.0,
    -0.19509032201612827,
    -0.38268343236508977,
    -0.55557023301960222,
    -0.70710678118654752,
    -0.83146961230254524,
    -0.92387953251128674,
    -0.98078528040323043,
    -1.0,
    -0.98078528040323043,
    -0.92387953251128674,
    -0.83146961230254524,
    -0.70710678118654752,
    -0.55557023301960222,
    -0.38268343236508977,
    -0.19509032201612827,
     0.0,
     0.19509032201612827,
     0.38268343236508977,
     0.55557023301960222,
     0.70710678118654752,
     0.83146961230254524,
     0.92387953251128674,
     0.98078528040323043,
  };
  // C[0][j] = sqrt(1/8); C[i][j] = 0.5 * cos(pi*i*(2j+1)/16)
  return (i == 0) ? 0.35355339059327373f
                  : (float)(0.5 * COS16[(i * (2 * j + 1)) % 32]);
}

// ---------------------------------------------------------------------------
// Setup: noise MLP (exact-erf GELU) in fp64 -> Q (64 floats) in d_ws.
// ---------------------------------------------------------------------------
__global__ void setup_q(const float* __restrict__ noise,
                        const float* __restrict__ qmat,
                        const float* __restrict__ qmw,
                        const float* __restrict__ w1, const float* __restrict__ b1,
                        const float* __restrict__ w2, const float* __restrict__ b2,
                        const float* __restrict__ w3, const float* __restrict__ b3,
                        float* __restrict__ qout) {
  __shared__ double coeff[16];
  if (threadIdx.x == 0) {
    const double inv_sqrt2 = 0.70710678118654752;
    double h1[16], h2[16], nr[18];
    double nl = (double)noise[0];
    for (int j = 0; j < 16; ++j) {
      double v = nl * (double)w1[j] + (double)b1[j];
      h1[j] = 0.5 * v * (1.0 + erf(v * inv_sqrt2));
    }
    for (int j = 0; j < 16; ++j) {
      double v = (double)b2[j];
      for (int i = 0; i < 16; ++i) v += h1[i] * (double)w2[i * 16 + j];
      h2[j] = 0.5 * v * (1.0 + erf(v * inv_sqrt2));
    }
    for (int j = 0; j < 18; ++j) {
      double v = (double)b3[j];
      for (int i = 0; i < 16; ++i) v += h2[i] * (double)w3[i * 18 + j];
      nr[j] = v;
    }
    double mx = (double)qmw[0];
    for (int i = 1; i < 16; ++i) mx = fmax(mx, (double)qmw[i]);
    double e[16], s = 0.0;
    for (int i = 0; i < 16; ++i) { e[i] = exp((double)qmw[i] - mx); s += e[i]; }
    for (int i = 0; i < 16; ++i)
      coeff[i] = (e[i] / s * nr[0] + nr[1]) * nr[2 + i];
  }
  __syncthreads();
  const int t = threadIdx.x;  // 64 threads, one Q entry each
  double q = 0.0;
  for (int i = 0; i < 16; ++i) q += coeff[i] * (double)qmat[i * 64 + t];
  qout[t] = (float)q;
}

// ---------------------------------------------------------------------------
// In-register 8x8 transpose across 8 lanes (rows are 8 lanes apart: lane
// bits 3..5 carry the row index r; lane bits 0..2 carry the block index and
// are untouched by masks 8/16/32).
// Stage k exchanges: lane(row-bit k = 0).v[j|bit] <-> lane(row-bit k = 1).v[j].
// ---------------------------------------------------------------------------
__device__ __forceinline__ void transpose8(float v[8], int r) {
#pragma unroll
  for (int k = 0; k < 3; ++k) {
    const int bit = 1 << k;
    const int lm = 8 << k;
    const bool rb = (r >> k) & 1;
#pragma unroll
    for (int j0 = 0; j0 < 8; ++j0) {
      if (j0 & bit) continue;          // unrolled: compile-time skip
      const int j1 = j0 | bit;
      float s = rb ? v[j0] : v[j1];
      float t = __shfl_xor(s, lm, 64);
      v[j0] = rb ? t : v[j0];
      v[j1] = rb ? v[j1] : t;
    }
  }
}

// ---------------------------------------------------------------------------
// Main: one wave per 8-row band (8 blocks); lane = (r<<3)|q : row r, block q.
// Chain: Y = X C^T ; T ; W = Y' C^T (= D^T) ; mask Q^T ; G = P' C ; T ;
//        L = G' C (= low). high = X - low per-lane.
// ---------------------------------------------------------------------------
__global__ __launch_bounds__(256, 8) void dct_main(const float* __restrict__ x,
                                                   const float* __restrict__ qg,
                                                   float* __restrict__ lo,
                                                   float* __restrict__ hi) {
  __shared__ float Qs[64];
  const int tid = threadIdx.x;
  if (tid < 64) Qs[tid] = qg[tid];
  __syncthreads();

  const int lane = tid & 63;
  const int r = lane >> 3;                       // row within block
  const int wave_id = (blockIdx.x * 256 + tid) >> 6;  // band id, 0..65535
  // band base (floats): image n = wave_id>>3 (4096 floats), band b = wave_id&7
  const int base = ((wave_id >> 3) << 12) | ((wave_id & 7) << 9);
  const int off = base + r * 64 + (lane & 7) * 8;

  // Q^T row r: qv[j] = Q[j][r]
  float qv[8];
#pragma unroll
  for (int j = 0; j < 8; ++j) qv[j] = Qs[j * 8 + r];

  const float* px = x + off;
  float X[8];
  {
    const f4 a = __builtin_nontemporal_load(reinterpret_cast<const f4*>(px));
    const f4 b = __builtin_nontemporal_load(reinterpret_cast<const f4*>(px + 4));
    X[0] = a.x; X[1] = a.y; X[2] = a.z; X[3] = a.w;
    X[4] = b.x; X[5] = b.y; X[6] = b.z; X[7] = b.w;
  }

  float A[8], B[8];
  // Stage 1: A = (X C^T) row:  A[j] = sum_l X[l] * C[j][l]
#pragma unroll
  for (int j = 0; j < 8; ++j) {
    float s = X[0] * cc(j, 0);
#pragma unroll
    for (int l = 1; l < 8; ++l) s = fmaf(X[l], cc(j, l), s);
    A[j] = s;
  }
  transpose8(A, r);   // lane now holds column r of Y = X C^T
  // Stage 2: B = (Y^T C^T) row = D^T row r  (D = C X C^T)
#pragma unroll
  for (int j = 0; j < 8; ++j) {
    float s = A[0] * cc(j, 0);
#pragma unroll
    for (int l = 1; l < 8; ++l) s = fmaf(A[l], cc(j, l), s);
    B[j] = s * qv[j];      // fused mask: (D o Q)^T row r
  }
  // Stage 3: A = (P^T C) row:  A[j] = sum_k B[k] * C[k][j]
#pragma unroll
  for (int j = 0; j < 8; ++j) {
    float s = B[0] * cc(0, j);
#pragma unroll
    for (int k = 1; k < 8; ++k) s = fmaf(B[k], cc(k, j), s);
    A[j] = s;
  }
  transpose8(A, r);   // lane now holds row r of C^T P
  // Stage 4: B = (G' C) row = low row r
#pragma unroll
  for (int j = 0; j < 8; ++j) {
    float s = A[0] * cc(0, j);
#pragma unroll
    for (int k = 1; k < 8; ++k) s = fmaf(A[k], cc(k, j), s);
    B[j] = s;
  }

  float* plo = lo + off;
  float* phi = hi + off;
  {
    f4 a = {B[0], B[1], B[2], B[3]};
    f4 b = {B[4], B[5], B[6], B[7]};
    *reinterpret_cast<f4*>(plo)     = a;
    *reinterpret_cast<f4*>(plo + 4) = b;
    f4 c = {X[0] - B[0], X[1] - B[1], X[2] - B[2], X[3] - B[3]};
    f4 d = {X[4] - B[4], X[5] - B[5], X[6] - B[6], X[7] - B[7]};
    *reinterpret_cast<f4*>(phi)     = c;
    *reinterpret_cast<f4*>(phi + 4) = d;
  }
}

extern "C" void kernel_launch(void* const* d_in, const int* in_sizes, int n_in,
                              void* d_out, int out_size, void* d_ws, size_t ws_size,
                              hipStream_t stream) {
  const float* x   = (const float*)d_in[0];
  const float* nl  = (const float*)d_in[1];
  const float* qm  = (const float*)d_in[2];
  const float* qmw = (const float*)d_in[3];
  const float* w1  = (const float*)d_in[4];
  const float* b1  = (const float*)d_in[5];
  const float* w2  = (const float*)d_in[6];
  const float* b2  = (const float*)d_in[7];
  const float* w3  = (const float*)d_in[8];
  const float* b3  = (const float*)d_in[9];

  const int n_elem = in_sizes[0];          // 33554432
  float* lo = (float*)d_out;
  float* hi = lo + n_elem;
  float* q  = (float*)d_ws;                // 64 floats

  setup_q<<<1, 64, 0, stream>>>(nl, qm, qmw, w1, b1, w2, b2, w3, b3, q);

  const int n_bands = n_elem >> 9;         // 65536 bands (8 rows x 64 cols)
  const int grid = (n_bands * 64) / 256;   // 16384 workgroups of 256 (4 waves)
  dct_main<<<grid, 256, 0, stream>>>(x, q, lo, hi);
}